// Round 9
// baseline (1226.176 us; speedup 1.0000x reference)
//
#include <hip/hip_runtime.h>
#include <hip/hip_bf16.h>

#define H 125
#define G4 500      // 4*H
#define NN 1024
#define DMLP 100

// exp-argument scales folded into weights/xg: sigmoid(x) = rcp(1 + 2^(-x*log2e))
#define SCL1 (-1.4426950408889634f)   // i, f, o rows
#define SCL2 (-2.8853900817779268f)   // g rows (tanh = 2*sigmoid(2x)-1)

typedef __attribute__((ext_vector_type(4))) float f32x4;
typedef __attribute__((ext_vector_type(4))) int   i32x4;
typedef __attribute__((ext_vector_type(8))) int   i32x8;

__device__ __forceinline__ float frcp(float x) { return __builtin_amdgcn_rcpf(x); }
__device__ __forceinline__ float fexp2(float x) {
    float r;
    asm("v_exp_f32 %0, %1" : "=v"(r) : "v"(x));
    return r;
}

// f32 -> f32 rounded to bf16 precision (low 16 mantissa bits zero).
__device__ __forceinline__ float bf16_quant(float v) {
    return __bfloat162float(__float2bfloat16(v));
}

// ---------------------------------------------------------------- embedding
__global__ void embed_k(const int* __restrict__ wid, const int* __restrict__ pid,
                        const float* __restrict__ wemb, const float* __restrict__ pemb,
                        float* __restrict__ emb)
{
    int t = blockIdx.x;
    int i = threadIdx.x;
    if (i < 100)      emb[t * H + i] = wemb[wid[t] * 100 + i];
    else if (i < H)   emb[t * H + i] = pemb[pid[t] * 25 + (i - 100)];
}

// ---------------------------------------------- input GEMM: xg4 = x@Wih.T + b
// Output layout [t][u][4]: xg4[t*512 + u*4 + g], PRE-SCALED by SCL1/SCL2 so
// the scan's sigmoids need no argument multiply. Pads u>=125 zero.
template<int K>
__global__ __launch_bounds__(512) void ingemm4_k(
    const float* __restrict__ x,
    const float* __restrict__ wf, const float* __restrict__ bif, const float* __restrict__ bhf,
    const float* __restrict__ wb, const float* __restrict__ bib, const float* __restrict__ bhb,
    float* __restrict__ xg4f, float* __restrict__ xg4b)
{
    __shared__ float xs[8][K];
    const int dir = blockIdx.y;
    const float* __restrict__ w  = dir ? wb  : wf;
    const float* __restrict__ bi = dir ? bib : bif;
    const float* __restrict__ bh = dir ? bhb : bhf;
    float* __restrict__ xg       = dir ? xg4b : xg4f;

    const int t0  = blockIdx.x * 8;
    const int tid = threadIdx.x;
    for (int i = tid; i < 8 * K; i += 512) {
        int r = i / K;
        xs[r][i - r * K] = x[t0 * K + i];
    }
    __syncthreads();

    if (tid < G4) {
        const int g = tid / 125;
        const int u = tid - g * 125;
        const float sg = (g == 2) ? SCL2 : SCL1;
        const float* wr = w + tid * K;
        float base = bi[tid] + bh[tid];
        float acc[8];
#pragma unroll
        for (int tt = 0; tt < 8; ++tt) acc[tt] = base;
        for (int k = 0; k < K; ++k) {
            float wv = wr[k];
#pragma unroll
            for (int tt = 0; tt < 8; ++tt) acc[tt] += wv * xs[tt][k];
        }
#pragma unroll
        for (int tt = 0; tt < 8; ++tt) xg[(t0 + tt) * 512 + u * 4 + g] = acc[tt] * sg;
    } else {
        const int qq = tid - G4;   // pad slots 500..511
#pragma unroll
        for (int tt = 0; tt < 8; ++tt) xg[(t0 + tt) * 512 + G4 + qq] = 0.f;
    }
}

// --------------------------------- Whh -> fp8(e4m3) MFMA A-fragment prep
// Rows pre-scaled by SCL1/SCL2 (same fold as xg). Fragment for MX mfma
// 16x16x128: lane l holds rows R = tg*16 + (l&15), k = (l>>4)*32 + e.
__global__ __launch_bounds__(64) void whhprep8_k(
    const float* __restrict__ whh_f, const float* __restrict__ whh_b,
    int* __restrict__ out)
{
    const int dir = blockIdx.y;
    const float* __restrict__ whh = dir ? whh_b : whh_f;
    const int tg = blockIdx.x;        // 0..31
    const int l  = threadIdx.x;
    const int R  = tg * 16 + (l & 15);
    const int u  = R >> 2, g = R & 3;
    const float sg = (g == 2) ? SCL2 : SCL1;
    const int kb = (l >> 4) * 32;
    float f[32];
#pragma unroll
    for (int e = 0; e < 32; ++e) {
        const int k = kb + e;
        f[e] = (u < H && k < H) ? whh[(g * H + u) * H + k] * sg : 0.f;
    }
    int* dst = out + ((dir * 32 + tg) * 64 + l) * 8;
#pragma unroll
    for (int j = 0; j < 8; ++j) {
        int lo = __builtin_amdgcn_cvt_pk_fp8_f32(f[4 * j + 0], f[4 * j + 1], 0,  false);
        int wv = __builtin_amdgcn_cvt_pk_fp8_f32(f[4 * j + 2], f[4 * j + 3], lo, true);
        dst[j] = wv;
    }
}

// ------------------------------------------------------------- LSTM scan v7
// grid = 2 (dir), block = 256 (4 waves). Wave w: row-tiles 8w..8w+7.
// A = fp8 Whh (pre-scaled) in VGPRs, K=128 per MX MFMA. B = h fp8 from LDS.
// acc init = pre-scaled xg. Activations: rcp(1+2^G) directly (no arg mul).
__global__ __launch_bounds__(256, 1) void lstm_scan7_k(
    const float* __restrict__ xg_f, const float* __restrict__ xg_b,
    const int* __restrict__ whhA,
    float* __restrict__ hout)   // [NN][250]
{
    __shared__ __align__(16) unsigned char hb8[2][128];
    const int dir = blockIdx.x;
    const float* __restrict__ xg = dir ? xg_b : xg_f;
    const int col = dir ? H : 0;

    const int tid = threadIdx.x;
    const int w = tid >> 6;
    const int l = tid & 63;
    const int q = l >> 4;          // k-block group / D-row group
    const int c = l & 15;          // replicated column

    i32x8 A[8];
    const i32x8* Ab = (const i32x8*)whhA;
#pragma unroll
    for (int rt = 0; rt < 8; ++rt)
        A[rt] = Ab[(dir * 32 + w * 8 + rt) * 64 + l];

    if (tid < 128) { hb8[0][tid] = 0; hb8[1][tid] = 0; }
    __syncthreads();

    const int rsel = c & 7;
    const int usel = 32 * w + 4 * rsel + q;   // unit this lane activates
    const bool writer = (c < 8);
    const int xb = 128 * w + 4 * q;           // xg base; tile rt at +16*rt

    float cst = 0.f;
    int pp = 0;
    auto T = [&](int s) { return dir ? (NN - 1 - s) : s; };

    auto LOADALL = [&](int s_, f32x4 (&dst)[8]) {
        const int sc = (s_ < NN) ? s_ : NN - 1;
        const float* base = xg + T(sc) * 512 + xb;
#pragma unroll
        for (int rt = 0; rt < 8; ++rt)
            dst[rt] = *(const f32x4*)(base + 16 * rt);
    };

    auto STEP = [&](int t, const f32x4 (&x)[8]) {
        const unsigned char* hr = hb8[pp] + 32 * q;
        i32x4 blo = *(const i32x4*)hr;
        i32x4 bhi = *(const i32x4*)(hr + 16);
        i32x8 B;
        B[0] = blo[0]; B[1] = blo[1]; B[2] = blo[2]; B[3] = blo[3];
        B[4] = bhi[0]; B[5] = bhi[1]; B[6] = bhi[2]; B[7] = bhi[3];
        f32x4 a0 = __builtin_amdgcn_mfma_scale_f32_16x16x128_f8f6f4(
            A[0], B, x[0], 0, 0, 0, 0x7F7F7F7F, 0, 0x7F7F7F7F);
        f32x4 a1 = __builtin_amdgcn_mfma_scale_f32_16x16x128_f8f6f4(
            A[1], B, x[1], 0, 0, 0, 0x7F7F7F7F, 0, 0x7F7F7F7F);
        f32x4 a2 = __builtin_amdgcn_mfma_scale_f32_16x16x128_f8f6f4(
            A[2], B, x[2], 0, 0, 0, 0x7F7F7F7F, 0, 0x7F7F7F7F);
        f32x4 a3 = __builtin_amdgcn_mfma_scale_f32_16x16x128_f8f6f4(
            A[3], B, x[3], 0, 0, 0, 0x7F7F7F7F, 0, 0x7F7F7F7F);
        f32x4 a4 = __builtin_amdgcn_mfma_scale_f32_16x16x128_f8f6f4(
            A[4], B, x[4], 0, 0, 0, 0x7F7F7F7F, 0, 0x7F7F7F7F);
        f32x4 a5 = __builtin_amdgcn_mfma_scale_f32_16x16x128_f8f6f4(
            A[5], B, x[5], 0, 0, 0, 0x7F7F7F7F, 0, 0x7F7F7F7F);
        f32x4 a6 = __builtin_amdgcn_mfma_scale_f32_16x16x128_f8f6f4(
            A[6], B, x[6], 0, 0, 0, 0x7F7F7F7F, 0, 0x7F7F7F7F);
        f32x4 a7 = __builtin_amdgcn_mfma_scale_f32_16x16x128_f8f6f4(
            A[7], B, x[7], 0, 0, 0, 0x7F7F7F7F, 0, 0x7F7F7F7F);

        // 3-level select of acc[c&7]
        f32x4 s0 = (c & 1) ? a1 : a0;
        f32x4 s1 = (c & 1) ? a3 : a2;
        f32x4 s2 = (c & 1) ? a5 : a4;
        f32x4 s3 = (c & 1) ? a7 : a6;
        f32x4 u0 = (c & 2) ? s1 : s0;
        f32x4 u1 = (c & 2) ? s3 : s2;
        f32x4 gv = (c & 4) ? u1 : u0;

        // gates arrive pre-scaled: sigmoid = rcp(1 + 2^G), no argument mul.
        const float ai = frcp(1.f + fexp2(gv.x));
        const float af = frcp(1.f + fexp2(gv.y));
        const float ag = 2.f * frcp(1.f + fexp2(gv.z)) - 1.f;
        const float ao = frcp(1.f + fexp2(gv.w));
        cst = af * cst + ai * ag;
        const float th = 2.f * frcp(1.f + fexp2(cst * SCL2)) - 1.f;
        const float hv = ao * th;
        if (writer) {
            int pk = __builtin_amdgcn_cvt_pk_fp8_f32(hv, 0.f, 0, false);
            hb8[pp ^ 1][usel] = (unsigned char)(pk & 0xFF);
        }
        asm volatile("s_waitcnt lgkmcnt(0)" ::: "memory");
        __builtin_amdgcn_s_barrier();
        __builtin_amdgcn_sched_barrier(0);
        // off the barrier-arrival path:
        if (writer && usel < H) hout[t * 250 + col + usel] = hv;
        pp ^= 1;
    };

    f32x4 P[8], Qr[8], N0[8], N1[8];
    LOADALL(0, P);
    LOADALL(1, Qr);
#pragma unroll 1
    for (int s = 0; s < NN; s += 4) {
        LOADALL(s + 2, N0);
        LOADALL(s + 3, N1);
        STEP(T(s),     P);
        STEP(T(s + 1), Qr);
        LOADALL(s + 4, P);
        LOADALL(s + 5, Qr);
        STEP(T(s + 2), N0);
        STEP(T(s + 3), N1);
    }
}

// --------------------------------------------- heads/mods: h1@w.T + b, 8 t/block
__global__ __launch_bounds__(256) void headmod_k(
    const float* __restrict__ h1,
    const float* __restrict__ w1, const float* __restrict__ b1,
    const float* __restrict__ w2, const float* __restrict__ b2,
    float* __restrict__ heads, float* __restrict__ mods)
{
    __shared__ float xs[8][250];
    const int t0  = blockIdx.x * 8;
    const int tid = threadIdx.x;
    for (int i = tid; i < 8 * 250; i += 256) {
        int r = i / 250;
        xs[r][i - r * 250] = h1[t0 * 250 + i];
    }
    __syncthreads();

    int d; const float* w; float bb; float* o;
    if (tid < DMLP)                          { d = tid;       w = w1 + d * 250; bb = b1[d]; o = heads; }
    else if (tid >= 128 && tid < 128 + DMLP) { d = tid - 128; w = w2 + d * 250; bb = b2[d]; o = mods;  }
    else return;

    float acc[8];
#pragma unroll
    for (int tt = 0; tt < 8; ++tt) acc[tt] = bb;
    for (int k = 0; k < 250; ++k) {
        float wv = w[k];
#pragma unroll
        for (int tt = 0; tt < 8; ++tt) acc[tt] += wv * xs[tt][k];
    }
#pragma unroll
    for (int tt = 0; tt < 8; ++tt) o[(t0 + tt) * DMLP + d] = acc[tt];
}

// ----------------------------------------------------------------- scores
__global__ __launch_bounds__(256) void scores_k(
    const float* __restrict__ heads, const float* __restrict__ mods,
    const float* __restrict__ w3, const float* __restrict__ b3,
    float* __restrict__ out)
{
    __shared__ __align__(16) float hh[16][DMLP];
    __shared__ __align__(16) float mm[16][DMLP];
    __shared__ __align__(16) float ws3[DMLP];
    const int bh = blockIdx.y * 16, bm = blockIdx.x * 16;
    const int tid = threadIdx.x;
    for (int i = tid; i < 16 * DMLP; i += 256) {
        int r = i / DMLP, d = i - r * DMLP;
        hh[r][d] = heads[(bh + r) * DMLP + d];
        mm[r][d] = mods[(bm + r) * DMLP + d];
    }
    if (tid < DMLP) ws3[tid] = w3[tid];
    __syncthreads();

    const int tx = tid & 15, ty = tid >> 4;
    const f32x4* h4 = (const f32x4*)hh[ty];
    const f32x4* m4 = (const f32x4*)mm[tx];
    const f32x4* w4 = (const f32x4*)ws3;
    float acc = 0.f;
#pragma unroll
    for (int qq = 0; qq < DMLP / 4; ++qq) {
        f32x4 v  = h4[qq] + m4[qq];
        f32x4 wv = w4[qq];
#pragma unroll
        for (int e = 0; e < 4; ++e) {
            float th = 2.f * frcp(1.f + fexp2(v[e] * SCL2)) - 1.f;
            acc += wv[e] * th;
        }
    }
    acc += b3[0];
    const int hrow = bh + ty, mcol = bm + tx;
    float v = (hrow == mcol) ? -3.3895313892515355e38f : bf16_quant(acc);
    out[hrow * NN + mcol] = v;
}

// ----------------------------------------------------------------- launch
extern "C" void kernel_launch(void* const* d_in, const int* in_sizes, int n_in,
                              void* d_out, int out_size, void* d_ws, size_t ws_size,
                              hipStream_t stream)
{
    const int*   wid   = (const int*)d_in[0];
    const int*   pid   = (const int*)d_in[1];
    const float* wemb  = (const float*)d_in[3];
    const float* pemb  = (const float*)d_in[4];
    const float* wih0f = (const float*)d_in[5];
    const float* whh0f = (const float*)d_in[6];
    const float* bih0f = (const float*)d_in[7];
    const float* bhh0f = (const float*)d_in[8];
    const float* wih0b = (const float*)d_in[9];
    const float* whh0b = (const float*)d_in[10];
    const float* bih0b = (const float*)d_in[11];
    const float* bhh0b = (const float*)d_in[12];
    const float* wih1f = (const float*)d_in[13];
    const float* whh1f = (const float*)d_in[14];
    const float* bih1f = (const float*)d_in[15];
    const float* bhh1f = (const float*)d_in[16];
    const float* wih1b = (const float*)d_in[17];
    const float* whh1b = (const float*)d_in[18];
    const float* bih1b = (const float*)d_in[19];
    const float* bhh1b = (const float*)d_in[20];
    const float* w1    = (const float*)d_in[21];
    const float* b1    = (const float*)d_in[22];
    const float* w2    = (const float*)d_in[23];
    const float* b2    = (const float*)d_in[24];
    const float* w3    = (const float*)d_in[25];
    const float* b3    = (const float*)d_in[26];

    float* ws    = (float*)d_ws;
    float* emb   = ws;                  // 128000
    float* xgf   = ws + 128000;         // 524288
    float* xgb   = ws + 652288;         // 524288
    float* h0    = ws + 1176576;        // 256000
    float* h1    = ws + 1432576;        // 256000
    float* hd    = ws + 1688576;        // 102400
    float* md    = ws + 1790976;        // 102400
    int*   whhA0 = (int*)(ws + 1893376);  // 32768 i32
    int*   whhA1 = (int*)(ws + 1926144);  // 32768 i32

    embed_k<<<NN, 128, 0, stream>>>(wid, pid, wemb, pemb, emb);
    whhprep8_k<<<dim3(32, 2), 64, 0, stream>>>(whh0f, whh0b, whhA0);
    whhprep8_k<<<dim3(32, 2), 64, 0, stream>>>(whh1f, whh1b, whhA1);

    ingemm4_k<125><<<dim3(NN / 8, 2), 512, 0, stream>>>(
        emb, wih0f, bih0f, bhh0f, wih0b, bih0b, bhh0b, xgf, xgb);

    lstm_scan7_k<<<2, 256, 0, stream>>>(xgf, xgb, whhA0, h0);

    ingemm4_k<250><<<dim3(NN / 8, 2), 512, 0, stream>>>(
        h0, wih1f, bih1f, bhh1f, wih1b, bih1b, bhh1b, xgf, xgb);

    lstm_scan7_k<<<2, 256, 0, stream>>>(xgf, xgb, whhA1, h1);

    headmod_k<<<NN / 8, 256, 0, stream>>>(h1, w1, b1, w2, b2, hd, md);

    scores_k<<<dim3(NN / 16, NN / 16), 256, 0, stream>>>(hd, md, w3, b3, (float*)d_out);
}

// Round 10
// 1077.088 us; speedup vs baseline: 1.1384x; 1.1384x over previous
//
#include <hip/hip_runtime.h>
#include <hip/hip_bf16.h>

#define H 125
#define G4 500      // 4*H
#define NN 1024
#define DMLP 100

// exp-argument scales folded into weights/xg: sigmoid(x) = rcp(1 + 2^(-x*log2e))
#define SCL1 (-1.4426950408889634f)   // i, f, o rows
#define SCL2 (-2.8853900817779268f)   // g rows (tanh = 2*sigmoid(2x)-1)

typedef __attribute__((ext_vector_type(4))) float f32x4;
typedef __attribute__((ext_vector_type(4))) int   i32x4;
typedef __attribute__((ext_vector_type(8))) int   i32x8;

__device__ __forceinline__ float frcp(float x) { return __builtin_amdgcn_rcpf(x); }
__device__ __forceinline__ float fexp2(float x) {
    float r;
    asm("v_exp_f32 %0, %1" : "=v"(r) : "v"(x));
    return r;
}

// f32 -> f32 rounded to bf16 precision (low 16 mantissa bits zero).
__device__ __forceinline__ float bf16_quant(float v) {
    return __bfloat162float(__float2bfloat16(v));
}

// ----------------- layer-0 input GEMM with fused embedding gather
// xg4[t*512 + u*4 + g] = (emb[t] @ Wih.T + b)[g*125+u] * SCL, pads zero.
__global__ __launch_bounds__(512) void ingemm4a_k(
    const int* __restrict__ wid, const int* __restrict__ pid,
    const float* __restrict__ wemb, const float* __restrict__ pemb,
    const float* __restrict__ wf, const float* __restrict__ bif, const float* __restrict__ bhf,
    const float* __restrict__ wb, const float* __restrict__ bib, const float* __restrict__ bhb,
    float* __restrict__ xg4f, float* __restrict__ xg4b)
{
    __shared__ float xs[8][125];
    const int dir = blockIdx.y;
    const float* __restrict__ w  = dir ? wb  : wf;
    const float* __restrict__ bi = dir ? bib : bif;
    const float* __restrict__ bh = dir ? bhb : bhf;
    float* __restrict__ xg       = dir ? xg4b : xg4f;

    const int t0  = blockIdx.x * 8;
    const int tid = threadIdx.x;
    for (int i = tid; i < 8 * 125; i += 512) {
        int r = i / 125, k = i - r * 125;
        int t = t0 + r;
        xs[r][k] = (k < 100) ? wemb[wid[t] * 100 + k] : pemb[pid[t] * 25 + (k - 100)];
    }
    __syncthreads();

    if (tid < G4) {
        const int g = tid / 125;
        const int u = tid - g * 125;
        const float sg = (g == 2) ? SCL2 : SCL1;
        const float* wr = w + tid * 125;
        float base = bi[tid] + bh[tid];
        float acc[8];
#pragma unroll
        for (int tt = 0; tt < 8; ++tt) acc[tt] = base;
        for (int k = 0; k < 125; ++k) {
            float wv = wr[k];
#pragma unroll
            for (int tt = 0; tt < 8; ++tt) acc[tt] += wv * xs[tt][k];
        }
#pragma unroll
        for (int tt = 0; tt < 8; ++tt) xg[(t0 + tt) * 512 + u * 4 + g] = acc[tt] * sg;
    } else {
        const int qq = tid - G4;
#pragma unroll
        for (int tt = 0; tt < 8; ++tt) xg[(t0 + tt) * 512 + G4 + qq] = 0.f;
    }
}

// ---------------------------------------------- layer-1 input GEMM (K=250)
__global__ __launch_bounds__(512) void ingemm4_k(
    const float* __restrict__ x,
    const float* __restrict__ wf, const float* __restrict__ bif, const float* __restrict__ bhf,
    const float* __restrict__ wb, const float* __restrict__ bib, const float* __restrict__ bhb,
    float* __restrict__ xg4f, float* __restrict__ xg4b)
{
    __shared__ float xs[8][250];
    const int dir = blockIdx.y;
    const float* __restrict__ w  = dir ? wb  : wf;
    const float* __restrict__ bi = dir ? bib : bif;
    const float* __restrict__ bh = dir ? bhb : bhf;
    float* __restrict__ xg       = dir ? xg4b : xg4f;

    const int t0  = blockIdx.x * 8;
    const int tid = threadIdx.x;
    for (int i = tid; i < 8 * 250; i += 512) {
        int r = i / 250;
        xs[r][i - r * 250] = x[t0 * 250 + i];
    }
    __syncthreads();

    if (tid < G4) {
        const int g = tid / 125;
        const int u = tid - g * 125;
        const float sg = (g == 2) ? SCL2 : SCL1;
        const float* wr = w + tid * 250;
        float base = bi[tid] + bh[tid];
        float acc[8];
#pragma unroll
        for (int tt = 0; tt < 8; ++tt) acc[tt] = base;
        for (int k = 0; k < 250; ++k) {
            float wv = wr[k];
#pragma unroll
            for (int tt = 0; tt < 8; ++tt) acc[tt] += wv * xs[tt][k];
        }
#pragma unroll
        for (int tt = 0; tt < 8; ++tt) xg[(t0 + tt) * 512 + u * 4 + g] = acc[tt] * sg;
    } else {
        const int qq = tid - G4;
#pragma unroll
        for (int tt = 0; tt < 8; ++tt) xg[(t0 + tt) * 512 + G4 + qq] = 0.f;
    }
}

// --------------------------------- Whh -> fp8(e4m3) MFMA A-fragment prep
// Rows pre-scaled by SCL1/SCL2. Lane l holds rows R = tg*16 + (l&15),
// k = (l>>4)*32 + e (32 bytes). R = 4u+g interleaved.
__global__ __launch_bounds__(64) void whhprep8_k(
    const float* __restrict__ whh_f, const float* __restrict__ whh_b,
    int* __restrict__ out)
{
    const int dir = blockIdx.y;
    const float* __restrict__ whh = dir ? whh_b : whh_f;
    const int tg = blockIdx.x;        // 0..31
    const int l  = threadIdx.x;
    const int R  = tg * 16 + (l & 15);
    const int u  = R >> 2, g = R & 3;
    const float sg = (g == 2) ? SCL2 : SCL1;
    const int kb = (l >> 4) * 32;
    float f[32];
#pragma unroll
    for (int e = 0; e < 32; ++e) {
        const int k = kb + e;
        f[e] = (u < H && k < H) ? whh[(g * H + u) * H + k] * sg : 0.f;
    }
    int* dst = out + ((dir * 32 + tg) * 64 + l) * 8;
#pragma unroll
    for (int j = 0; j < 8; ++j) {
        int lo = __builtin_amdgcn_cvt_pk_fp8_f32(f[4 * j + 0], f[4 * j + 1], 0,  false);
        int wv = __builtin_amdgcn_cvt_pk_fp8_f32(f[4 * j + 2], f[4 * j + 3], lo, true);
        dst[j] = wv;
    }
}

// ------------------------------------------------------------- LSTM scan v8
// grid = 2 (dir), block = 1024 (16 waves, 4/SIMD -> matrix-pipe interleave).
// Wave w owns row-tiles 2w,2w+1 (units 8w..8w+7): 2 MX MFMA/step/wave.
// Key trick: lane (q,c) only reads D at its own column, so only tile (c&1)'s
// C-init matters -> C = the lane's own xg f32x4 for BOTH MFMAs (1 load/step).
__global__ __launch_bounds__(1024, 1) void lstm_scan8_k(
    const float* __restrict__ xg_f, const float* __restrict__ xg_b,
    const int* __restrict__ whhA,
    float* __restrict__ hout)   // [NN][250]
{
    __shared__ __align__(16) unsigned char hb8[2][128];
    const int dir = blockIdx.x;
    const float* __restrict__ xg = dir ? xg_b : xg_f;
    const int col = dir ? H : 0;

    const int tid = threadIdx.x;
    const int w = tid >> 6;        // 0..15
    const int l = tid & 63;
    const int q = l >> 4;          // k-block / D-row group
    const int c = l & 15;          // replicated column

    const i32x8* Ab = (const i32x8*)whhA;
    i32x8 A0 = Ab[(dir * 32 + w * 2 + 0) * 64 + l];
    i32x8 A1 = Ab[(dir * 32 + w * 2 + 1) * 64 + l];

    if (tid < 128) { hb8[0][tid] = 0; hb8[1][tid] = 0; }
    __syncthreads();

    const int rsel = c & 1;
    const int usel = 8 * w + 4 * rsel + q;    // unit this lane activates
    const bool writer = (c < 2);
    const int xoff = 32 * w + 16 * rsel + 4 * q;

    float cst = 0.f;
    int pp = 0;
    auto T = [&](int s) { return dir ? (NN - 1 - s) : s; };

    auto LOADX = [&](int s_) -> f32x4 {
        const int sc = (s_ < NN) ? s_ : NN - 1;
        return *(const f32x4*)(xg + T(sc) * 512 + xoff);
    };

    auto STEP = [&](int t, f32x4 x) {
        const unsigned char* hr = hb8[pp] + 32 * q;
        i32x4 blo = *(const i32x4*)hr;
        i32x4 bhi = *(const i32x4*)(hr + 16);
        i32x8 B;
        B[0] = blo[0]; B[1] = blo[1]; B[2] = blo[2]; B[3] = blo[3];
        B[4] = bhi[0]; B[5] = bhi[1]; B[6] = bhi[2]; B[7] = bhi[3];
        f32x4 a0 = __builtin_amdgcn_mfma_scale_f32_16x16x128_f8f6f4(
            A0, B, x, 0, 0, 0, 0x7F7F7F7F, 0, 0x7F7F7F7F);
        f32x4 a1 = __builtin_amdgcn_mfma_scale_f32_16x16x128_f8f6f4(
            A1, B, x, 0, 0, 0, 0x7F7F7F7F, 0, 0x7F7F7F7F);
        f32x4 gv = rsel ? a1 : a0;

        // gates arrive pre-scaled: sigmoid = rcp(1 + 2^G).
        const float ai = frcp(1.f + fexp2(gv.x));
        const float af = frcp(1.f + fexp2(gv.y));
        const float ag = 2.f * frcp(1.f + fexp2(gv.z)) - 1.f;
        const float ao = frcp(1.f + fexp2(gv.w));
        cst = af * cst + ai * ag;
        const float th = 2.f * frcp(1.f + fexp2(cst * SCL2)) - 1.f;
        const float hv = ao * th;
        if (writer) {
            int pk = __builtin_amdgcn_cvt_pk_fp8_f32(hv, 0.f, 0, false);
            hb8[pp ^ 1][usel] = (unsigned char)(pk & 0xFF);
        }
        asm volatile("s_waitcnt lgkmcnt(0)" ::: "memory");
        __builtin_amdgcn_s_barrier();
        __builtin_amdgcn_sched_barrier(0);
        if (writer && usel < H) hout[t * 250 + col + usel] = hv;
        pp ^= 1;
    };

    f32x4 p0 = LOADX(0), p1 = LOADX(1);
#pragma unroll 1
    for (int s = 0; s < NN; s += 4) {
        f32x4 n0 = LOADX(s + 2), n1 = LOADX(s + 3);
        STEP(T(s),     p0);
        STEP(T(s + 1), p1);
        p0 = LOADX(s + 4); p1 = LOADX(s + 5);
        STEP(T(s + 2), n0);
        STEP(T(s + 3), n1);
    }
}

// --------------------------------------------- heads/mods: h1@w.T + b
__global__ __launch_bounds__(256) void headmod_k(
    const float* __restrict__ h1,
    const float* __restrict__ w1, const float* __restrict__ b1,
    const float* __restrict__ w2, const float* __restrict__ b2,
    float* __restrict__ heads, float* __restrict__ mods)
{
    __shared__ float xs[8][250];
    const int t0  = blockIdx.x * 8;
    const int tid = threadIdx.x;
    for (int i = tid; i < 8 * 250; i += 256) {
        int r = i / 250;
        xs[r][i - r * 250] = h1[t0 * 250 + i];
    }
    __syncthreads();

    int d; const float* w; float bb; float* o;
    if (tid < DMLP)                          { d = tid;       w = w1 + d * 250; bb = b1[d]; o = heads; }
    else if (tid >= 128 && tid < 128 + DMLP) { d = tid - 128; w = w2 + d * 250; bb = b2[d]; o = mods;  }
    else return;

    float acc[8];
#pragma unroll
    for (int tt = 0; tt < 8; ++tt) acc[tt] = bb;
    for (int k = 0; k < 250; ++k) {
        float wv = w[k];
#pragma unroll
        for (int tt = 0; tt < 8; ++tt) acc[tt] += wv * xs[tt][k];
    }
#pragma unroll
    for (int tt = 0; tt < 8; ++tt) o[(t0 + tt) * DMLP + d] = acc[tt];
}

// ----------------------------------------------------------------- scores
__global__ __launch_bounds__(256) void scores_k(
    const float* __restrict__ heads, const float* __restrict__ mods,
    const float* __restrict__ w3, const float* __restrict__ b3,
    float* __restrict__ out)
{
    __shared__ __align__(16) float hh[16][DMLP];
    __shared__ __align__(16) float mm[16][DMLP];
    __shared__ __align__(16) float ws3[DMLP];
    const int bh = blockIdx.y * 16, bm = blockIdx.x * 16;
    const int tid = threadIdx.x;
    for (int i = tid; i < 16 * DMLP; i += 256) {
        int r = i / DMLP, d = i - r * DMLP;
        hh[r][d] = heads[(bh + r) * DMLP + d];
        mm[r][d] = mods[(bm + r) * DMLP + d];
    }
    if (tid < DMLP) ws3[tid] = w3[tid];
    __syncthreads();

    const int tx = tid & 15, ty = tid >> 4;
    const f32x4* h4 = (const f32x4*)hh[ty];
    const f32x4* m4 = (const f32x4*)mm[tx];
    const f32x4* w4 = (const f32x4*)ws3;
    float acc = 0.f;
#pragma unroll
    for (int qq = 0; qq < DMLP / 4; ++qq) {
        f32x4 v  = h4[qq] + m4[qq];
        f32x4 wv = w4[qq];
#pragma unroll
        for (int e = 0; e < 4; ++e) {
            float th = 2.f * frcp(1.f + fexp2(v[e] * SCL2)) - 1.f;
            acc += wv[e] * th;
        }
    }
    acc += b3[0];
    const int hrow = bh + ty, mcol = bm + tx;
    float v = (hrow == mcol) ? -3.3895313892515355e38f : bf16_quant(acc);
    out[hrow * NN + mcol] = v;
}

// ----------------------------------------------------------------- launch
extern "C" void kernel_launch(void* const* d_in, const int* in_sizes, int n_in,
                              void* d_out, int out_size, void* d_ws, size_t ws_size,
                              hipStream_t stream)
{
    const int*   wid   = (const int*)d_in[0];
    const int*   pid   = (const int*)d_in[1];
    const float* wemb  = (const float*)d_in[3];
    const float* pemb  = (const float*)d_in[4];
    const float* wih0f = (const float*)d_in[5];
    const float* whh0f = (const float*)d_in[6];
    const float* bih0f = (const float*)d_in[7];
    const float* bhh0f = (const float*)d_in[8];
    const float* wih0b = (const float*)d_in[9];
    const float* whh0b = (const float*)d_in[10];
    const float* bih0b = (const float*)d_in[11];
    const float* bhh0b = (const float*)d_in[12];
    const float* wih1f = (const float*)d_in[13];
    const float* whh1f = (const float*)d_in[14];
    const float* bih1f = (const float*)d_in[15];
    const float* bhh1f = (const float*)d_in[16];
    const float* wih1b = (const float*)d_in[17];
    const float* whh1b = (const float*)d_in[18];
    const float* bih1b = (const float*)d_in[19];
    const float* bhh1b = (const float*)d_in[20];
    const float* w1    = (const float*)d_in[21];
    const float* b1    = (const float*)d_in[22];
    const float* w2    = (const float*)d_in[23];
    const float* b2    = (const float*)d_in[24];
    const float* w3    = (const float*)d_in[25];
    const float* b3    = (const float*)d_in[26];

    float* ws    = (float*)d_ws;
    float* xgf   = ws;                  // 524288
    float* xgb   = ws + 524288;         // 524288
    float* h0    = ws + 1048576;        // 256000
    float* h1    = ws + 1304576;        // 256000
    float* hd    = ws + 1560576;        // 102400
    float* md    = ws + 1662976;        // 102400
    int*   whhA0 = (int*)(ws + 1765376);  // 32768 i32
    int*   whhA1 = (int*)(ws + 1798144);  // 32768 i32

    whhprep8_k<<<dim3(32, 2), 64, 0, stream>>>(whh0f, whh0b, whhA0);
    whhprep8_k<<<dim3(32, 2), 64, 0, stream>>>(whh1f, whh1b, whhA1);

    ingemm4a_k<<<dim3(NN / 8, 2), 512, 0, stream>>>(
        wid, pid, wemb, pemb,
        wih0f, bih0f, bhh0f, wih0b, bih0b, bhh0b, xgf, xgb);

    lstm_scan8_k<<<2, 1024, 0, stream>>>(xgf, xgb, whhA0, h0);

    ingemm4_k<<<dim3(NN / 8, 2), 512, 0, stream>>>(
        h0, wih1f, bih1f, bhh1f, wih1b, bih1b, bhh1b, xgf, xgb);

    lstm_scan8_k<<<2, 1024, 0, stream>>>(xgf, xgb, whhA1, h1);

    headmod_k<<<NN / 8, 256, 0, stream>>>(h1, w1, b1, w2, b2, hd, md);

    scores_k<<<dim3(NN / 16, NN / 16), 256, 0, stream>>>(hd, md, w3, b3, (float*)d_out);
}

// Round 11
// 1032.492 us; speedup vs baseline: 1.1876x; 1.0432x over previous
//
#include <hip/hip_runtime.h>
#include <hip/hip_bf16.h>

#define H 125
#define G4 500      // 4*H
#define NN 1024
#define DMLP 100

// exp-argument scales folded into weights/xg: sigmoid(x) = rcp(1 + 2^(-x*log2e))
#define SCL1 (-1.4426950408889634f)   // i, f, o rows
#define SCL2 (-2.8853900817779268f)   // g rows (tanh = 2*sigmoid(2x)-1)

typedef __attribute__((ext_vector_type(4))) float f32x4;
typedef __attribute__((ext_vector_type(4))) int   i32x4;
typedef __attribute__((ext_vector_type(8))) int   i32x8;

__device__ __forceinline__ float frcp(float x) { return __builtin_amdgcn_rcpf(x); }
__device__ __forceinline__ float fexp2(float x) {
    float r;
    asm("v_exp_f32 %0, %1" : "=v"(r) : "v"(x));
    return r;
}

// f32 -> f32 rounded to bf16 precision (low 16 mantissa bits zero).
__device__ __forceinline__ float bf16_quant(float v) {
    return __bfloat162float(__float2bfloat16(v));
}

// ----------------- layer-0 input GEMM with fused embedding gather
__global__ __launch_bounds__(512) void ingemm4a_k(
    const int* __restrict__ wid, const int* __restrict__ pid,
    const float* __restrict__ wemb, const float* __restrict__ pemb,
    const float* __restrict__ wf, const float* __restrict__ bif, const float* __restrict__ bhf,
    const float* __restrict__ wb, const float* __restrict__ bib, const float* __restrict__ bhb,
    float* __restrict__ xg4f, float* __restrict__ xg4b)
{
    __shared__ float xs[8][125];
    const int dir = blockIdx.y;
    const float* __restrict__ w  = dir ? wb  : wf;
    const float* __restrict__ bi = dir ? bib : bif;
    const float* __restrict__ bh = dir ? bhb : bhf;
    float* __restrict__ xg       = dir ? xg4b : xg4f;

    const int t0  = blockIdx.x * 8;
    const int tid = threadIdx.x;
    for (int i = tid; i < 8 * 125; i += 512) {
        int r = i / 125, k = i - r * 125;
        int t = t0 + r;
        xs[r][k] = (k < 100) ? wemb[wid[t] * 100 + k] : pemb[pid[t] * 25 + (k - 100)];
    }
    __syncthreads();

    if (tid < G4) {
        const int g = tid / 125;
        const int u = tid - g * 125;
        const float sg = (g == 2) ? SCL2 : SCL1;
        const float* wr = w + tid * 125;
        float base = bi[tid] + bh[tid];
        float acc[8];
#pragma unroll
        for (int tt = 0; tt < 8; ++tt) acc[tt] = base;
        for (int k = 0; k < 125; ++k) {
            float wv = wr[k];
#pragma unroll
            for (int tt = 0; tt < 8; ++tt) acc[tt] += wv * xs[tt][k];
        }
#pragma unroll
        for (int tt = 0; tt < 8; ++tt) xg[(t0 + tt) * 512 + u * 4 + g] = acc[tt] * sg;
    } else {
        const int qq = tid - G4;
#pragma unroll
        for (int tt = 0; tt < 8; ++tt) xg[(t0 + tt) * 512 + G4 + qq] = 0.f;
    }
}

// ---------------------------------------------- layer-1 input GEMM (K=250)
__global__ __launch_bounds__(512) void ingemm4_k(
    const float* __restrict__ x,
    const float* __restrict__ wf, const float* __restrict__ bif, const float* __restrict__ bhf,
    const float* __restrict__ wb, const float* __restrict__ bib, const float* __restrict__ bhb,
    float* __restrict__ xg4f, float* __restrict__ xg4b)
{
    __shared__ float xs[8][250];
    const int dir = blockIdx.y;
    const float* __restrict__ w  = dir ? wb  : wf;
    const float* __restrict__ bi = dir ? bib : bif;
    const float* __restrict__ bh = dir ? bhb : bhf;
    float* __restrict__ xg       = dir ? xg4b : xg4f;

    const int t0  = blockIdx.x * 8;
    const int tid = threadIdx.x;
    for (int i = tid; i < 8 * 250; i += 512) {
        int r = i / 250;
        xs[r][i - r * 250] = x[t0 * 250 + i];
    }
    __syncthreads();

    if (tid < G4) {
        const int g = tid / 125;
        const int u = tid - g * 125;
        const float sg = (g == 2) ? SCL2 : SCL1;
        const float* wr = w + tid * 250;
        float base = bi[tid] + bh[tid];
        float acc[8];
#pragma unroll
        for (int tt = 0; tt < 8; ++tt) acc[tt] = base;
        for (int k = 0; k < 250; ++k) {
            float wv = wr[k];
#pragma unroll
            for (int tt = 0; tt < 8; ++tt) acc[tt] += wv * xs[tt][k];
        }
#pragma unroll
        for (int tt = 0; tt < 8; ++tt) xg[(t0 + tt) * 512 + u * 4 + g] = acc[tt] * sg;
    } else {
        const int qq = tid - G4;
#pragma unroll
        for (int tt = 0; tt < 8; ++tt) xg[(t0 + tt) * 512 + G4 + qq] = 0.f;
    }
}

// --------------------------------- Whh -> fp8(e4m3) MFMA A-fragment prep
__global__ __launch_bounds__(64) void whhprep8_k(
    const float* __restrict__ whh_f, const float* __restrict__ whh_b,
    int* __restrict__ out)
{
    const int dir = blockIdx.y;
    const float* __restrict__ whh = dir ? whh_b : whh_f;
    const int tg = blockIdx.x;        // 0..31
    const int l  = threadIdx.x;
    const int R  = tg * 16 + (l & 15);
    const int u  = R >> 2, g = R & 3;
    const float sg = (g == 2) ? SCL2 : SCL1;
    const int kb = (l >> 4) * 32;
    float f[32];
#pragma unroll
    for (int e = 0; e < 32; ++e) {
        const int k = kb + e;
        f[e] = (u < H && k < H) ? whh[(g * H + u) * H + k] * sg : 0.f;
    }
    int* dst = out + ((dir * 32 + tg) * 64 + l) * 8;
#pragma unroll
    for (int j = 0; j < 8; ++j) {
        int lo = __builtin_amdgcn_cvt_pk_fp8_f32(f[4 * j + 0], f[4 * j + 1], 0,  false);
        int wv = __builtin_amdgcn_cvt_pk_fp8_f32(f[4 * j + 2], f[4 * j + 3], lo, true);
        dst[j] = wv;
    }
}

// ------------------------------------------------------------- LSTM scan v9
// grid = 2 (dir), block = 1024 (16 waves). Producer-consumer split per step:
// seg1: ALL waves do 2 MX MFMA (C = own-lane xg); 8 writer lanes/wave ds_write
//       their f32x4 gate vector to gates[128]. (no activation in MFMA waves)
// seg2: waves 0-1 only: 128 lanes each activate ONE unit (zero redundancy),
//       write fp8 h to hb8 + f32 h to hout. Two raw s_barriers per step.
__global__ __launch_bounds__(1024, 1) void lstm_scan9_k(
    const float* __restrict__ xg_f, const float* __restrict__ xg_b,
    const int* __restrict__ whhA,
    float* __restrict__ hout)   // [NN][250]
{
    __shared__ __align__(16) unsigned char hb8[128];     // fp8 h (single buf)
    __shared__ __align__(16) float gates[128 * 4];       // f32 gate vecs
    const int dir = blockIdx.x;
    const float* __restrict__ xg = dir ? xg_b : xg_f;
    const int col = dir ? H : 0;

    const int tid = threadIdx.x;
    const int w = tid >> 6;        // 0..15
    const int l = tid & 63;
    const int q = l >> 4;          // k-block / D-row group
    const int c = l & 15;          // replicated column

    const i32x8* Ab = (const i32x8*)whhA;
    i32x8 A0 = Ab[(dir * 32 + w * 2 + 0) * 64 + l];
    i32x8 A1 = Ab[(dir * 32 + w * 2 + 1) * 64 + l];

    if (tid < 128) hb8[tid] = 0;
    __syncthreads();

    const int usel = 8 * w + 4 * (c & 1) + q;   // unit of this lane's gv
    const bool writer = (c < 2);
    const int xoff = 32 * w + 16 * (c & 1) + 4 * q;

    float cst = 0.f;                 // live only in act lanes (tid<128)
    auto T = [&](int s) { return dir ? (NN - 1 - s) : s; };

    auto LOADX = [&](int s_) -> f32x4 {
        const int sc = (s_ < NN) ? s_ : NN - 1;
        return *(const f32x4*)(xg + T(sc) * 512 + xoff);
    };

    auto STEP = [&](int t, f32x4 x) {
        // ---- seg1: MFMA + gate publish (all waves)
        i32x8 B = *(const i32x8*)(hb8 + 32 * q);
        f32x4 a0 = __builtin_amdgcn_mfma_scale_f32_16x16x128_f8f6f4(
            A0, B, x, 0, 0, 0, 0x7F7F7F7F, 0, 0x7F7F7F7F);
        f32x4 a1 = __builtin_amdgcn_mfma_scale_f32_16x16x128_f8f6f4(
            A1, B, x, 0, 0, 0, 0x7F7F7F7F, 0, 0x7F7F7F7F);
        if (writer) {
            f32x4 gv = (c & 1) ? a1 : a0;
            *(f32x4*)(gates + 4 * usel) = gv;
        }
        asm volatile("s_waitcnt lgkmcnt(0)" ::: "memory");
        __builtin_amdgcn_s_barrier();
        __builtin_amdgcn_sched_barrier(0);
        // ---- seg2: activation (waves 0-1 only; one lane per unit)
        if (tid < 128) {
            f32x4 g = *(const f32x4*)(gates + 4 * tid);
            const float ai = frcp(1.f + fexp2(g.x));
            const float af = frcp(1.f + fexp2(g.y));
            const float ag = 2.f * frcp(1.f + fexp2(g.z)) - 1.f;
            const float ao = frcp(1.f + fexp2(g.w));
            cst = af * cst + ai * ag;
            const float th = 2.f * frcp(1.f + fexp2(cst * SCL2)) - 1.f;
            const float hv = ao * th;
            int pk = __builtin_amdgcn_cvt_pk_fp8_f32(hv, 0.f, 0, false);
            hb8[tid] = (unsigned char)(pk & 0xFF);
            if (tid < H) hout[t * 250 + col + tid] = hv;
        }
        asm volatile("s_waitcnt lgkmcnt(0)" ::: "memory");
        __builtin_amdgcn_s_barrier();
        __builtin_amdgcn_sched_barrier(0);
    };

    f32x4 p0 = LOADX(0), p1 = LOADX(1);
#pragma unroll 1
    for (int s = 0; s < NN; s += 4) {
        f32x4 n0 = LOADX(s + 2), n1 = LOADX(s + 3);
        STEP(T(s),     p0);
        STEP(T(s + 1), p1);
        p0 = LOADX(s + 4); p1 = LOADX(s + 5);
        STEP(T(s + 2), n0);
        STEP(T(s + 3), n1);
    }
}

// --------------------------------------------- heads/mods: h1@w.T + b
__global__ __launch_bounds__(256) void headmod_k(
    const float* __restrict__ h1,
    const float* __restrict__ w1, const float* __restrict__ b1,
    const float* __restrict__ w2, const float* __restrict__ b2,
    float* __restrict__ heads, float* __restrict__ mods)
{
    __shared__ float xs[8][250];
    const int t0  = blockIdx.x * 8;
    const int tid = threadIdx.x;
    for (int i = tid; i < 8 * 250; i += 256) {
        int r = i / 250;
        xs[r][i - r * 250] = h1[t0 * 250 + i];
    }
    __syncthreads();

    int d; const float* w; float bb; float* o;
    if (tid < DMLP)                          { d = tid;       w = w1 + d * 250; bb = b1[d]; o = heads; }
    else if (tid >= 128 && tid < 128 + DMLP) { d = tid - 128; w = w2 + d * 250; bb = b2[d]; o = mods;  }
    else return;

    float acc[8];
#pragma unroll
    for (int tt = 0; tt < 8; ++tt) acc[tt] = bb;
    for (int k = 0; k < 250; ++k) {
        float wv = w[k];
#pragma unroll
        for (int tt = 0; tt < 8; ++tt) acc[tt] += wv * xs[tt][k];
    }
#pragma unroll
    for (int tt = 0; tt < 8; ++tt) o[(t0 + tt) * DMLP + d] = acc[tt];
}

// ----------------------------------------------------------------- scores
__global__ __launch_bounds__(256) void scores_k(
    const float* __restrict__ heads, const float* __restrict__ mods,
    const float* __restrict__ w3, const float* __restrict__ b3,
    float* __restrict__ out)
{
    __shared__ __align__(16) float hh[16][DMLP];
    __shared__ __align__(16) float mm[16][DMLP];
    __shared__ __align__(16) float ws3[DMLP];
    const int bh = blockIdx.y * 16, bm = blockIdx.x * 16;
    const int tid = threadIdx.x;
    for (int i = tid; i < 16 * DMLP; i += 256) {
        int r = i / DMLP, d = i - r * DMLP;
        hh[r][d] = heads[(bh + r) * DMLP + d];
        mm[r][d] = mods[(bm + r) * DMLP + d];
    }
    if (tid < DMLP) ws3[tid] = w3[tid];
    __syncthreads();

    const int tx = tid & 15, ty = tid >> 4;
    const f32x4* h4 = (const f32x4*)hh[ty];
    const f32x4* m4 = (const f32x4*)mm[tx];
    const f32x4* w4 = (const f32x4*)ws3;
    float acc = 0.f;
#pragma unroll
    for (int qq = 0; qq < DMLP / 4; ++qq) {
        f32x4 v  = h4[qq] + m4[qq];
        f32x4 wv = w4[qq];
#pragma unroll
        for (int e = 0; e < 4; ++e) {
            float th = 2.f * frcp(1.f + fexp2(v[e] * SCL2)) - 1.f;
            acc += wv[e] * th;
        }
    }
    acc += b3[0];
    const int hrow = bh + ty, mcol = bm + tx;
    float v = (hrow == mcol) ? -3.3895313892515355e38f : bf16_quant(acc);
    out[hrow * NN + mcol] = v;
}

// ----------------------------------------------------------------- launch
extern "C" void kernel_launch(void* const* d_in, const int* in_sizes, int n_in,
                              void* d_out, int out_size, void* d_ws, size_t ws_size,
                              hipStream_t stream)
{
    const int*   wid   = (const int*)d_in[0];
    const int*   pid   = (const int*)d_in[1];
    const float* wemb  = (const float*)d_in[3];
    const float* pemb  = (const float*)d_in[4];
    const float* wih0f = (const float*)d_in[5];
    const float* whh0f = (const float*)d_in[6];
    const float* bih0f = (const float*)d_in[7];
    const float* bhh0f = (const float*)d_in[8];
    const float* wih0b = (const float*)d_in[9];
    const float* whh0b = (const float*)d_in[10];
    const float* bih0b = (const float*)d_in[11];
    const float* bhh0b = (const float*)d_in[12];
    const float* wih1f = (const float*)d_in[13];
    const float* whh1f = (const float*)d_in[14];
    const float* bih1f = (const float*)d_in[15];
    const float* bhh1f = (const float*)d_in[16];
    const float* wih1b = (const float*)d_in[17];
    const float* whh1b = (const float*)d_in[18];
    const float* bih1b = (const float*)d_in[19];
    const float* bhh1b = (const float*)d_in[20];
    const float* w1    = (const float*)d_in[21];
    const float* b1    = (const float*)d_in[22];
    const float* w2    = (const float*)d_in[23];
    const float* b2    = (const float*)d_in[24];
    const float* w3    = (const float*)d_in[25];
    const float* b3    = (const float*)d_in[26];

    float* ws    = (float*)d_ws;
    float* xgf   = ws;                  // 524288
    float* xgb   = ws + 524288;         // 524288
    float* h0    = ws + 1048576;        // 256000
    float* h1    = ws + 1304576;        // 256000
    float* hd    = ws + 1560576;        // 102400
    float* md    = ws + 1662976;        // 102400
    int*   whhA0 = (int*)(ws + 1765376);  // 32768 i32
    int*   whhA1 = (int*)(ws + 1798144);  // 32768 i32

    whhprep8_k<<<dim3(32, 2), 64, 0, stream>>>(whh0f, whh0b, whhA0);
    whhprep8_k<<<dim3(32, 2), 64, 0, stream>>>(whh1f, whh1b, whhA1);

    ingemm4a_k<<<dim3(NN / 8, 2), 512, 0, stream>>>(
        wid, pid, wemb, pemb,
        wih0f, bih0f, bhh0f, wih0b, bih0b, bhh0b, xgf, xgb);

    lstm_scan9_k<<<2, 1024, 0, stream>>>(xgf, xgb, whhA0, h0);

    ingemm4_k<<<dim3(NN / 8, 2), 512, 0, stream>>>(
        h0, wih1f, bih1f, bhh1f, wih1b, bih1b, bhh1b, xgf, xgb);

    lstm_scan9_k<<<2, 1024, 0, stream>>>(xgf, xgb, whhA1, h1);

    headmod_k<<<NN / 8, 256, 0, stream>>>(h1, w1, b1, w2, b2, hd, md);

    scores_k<<<dim3(NN / 16, NN / 16), 256, 0, stream>>>(hd, md, w3, b3, (float*)d_out);
}

// Round 12
// 1004.004 us; speedup vs baseline: 1.2213x; 1.0284x over previous
//
#include <hip/hip_runtime.h>
#include <hip/hip_bf16.h>

#define H 125
#define G4 500      // 4*H
#define NN 1024
#define DMLP 100

// exp-argument scales folded into weights/xg: sigmoid(x) = rcp(1 + 2^(-x*log2e))
#define SCL1 (-1.4426950408889634f)   // i, f, o rows
#define SCL2 (-2.8853900817779268f)   // g rows (tanh = 2*sigmoid(2x)-1)

typedef __attribute__((ext_vector_type(4))) float f32x4;
typedef __attribute__((ext_vector_type(4))) int   i32x4;
typedef __attribute__((ext_vector_type(8))) int   i32x8;

__device__ __forceinline__ float frcp(float x) { return __builtin_amdgcn_rcpf(x); }
__device__ __forceinline__ float fexp2(float x) {
    float r;
    asm("v_exp_f32 %0, %1" : "=v"(r) : "v"(x));
    return r;
}

// f32 -> f32 rounded to bf16 precision (low 16 mantissa bits zero).
__device__ __forceinline__ float bf16_quant(float v) {
    return __bfloat162float(__float2bfloat16(v));
}

// ----------------- layer-0 input GEMM with fused embedding gather
__global__ __launch_bounds__(512) void ingemm4a_k(
    const int* __restrict__ wid, const int* __restrict__ pid,
    const float* __restrict__ wemb, const float* __restrict__ pemb,
    const float* __restrict__ wf, const float* __restrict__ bif, const float* __restrict__ bhf,
    const float* __restrict__ wb, const float* __restrict__ bib, const float* __restrict__ bhb,
    float* __restrict__ xg4f, float* __restrict__ xg4b)
{
    __shared__ float xs[8][125];
    const int dir = blockIdx.y;
    const float* __restrict__ w  = dir ? wb  : wf;
    const float* __restrict__ bi = dir ? bib : bif;
    const float* __restrict__ bh = dir ? bhb : bhf;
    float* __restrict__ xg       = dir ? xg4b : xg4f;

    const int t0  = blockIdx.x * 8;
    const int tid = threadIdx.x;
    for (int i = tid; i < 8 * 125; i += 512) {
        int r = i / 125, k = i - r * 125;
        int t = t0 + r;
        xs[r][k] = (k < 100) ? wemb[wid[t] * 100 + k] : pemb[pid[t] * 25 + (k - 100)];
    }
    __syncthreads();

    if (tid < G4) {
        const int g = tid / 125;
        const int u = tid - g * 125;
        const float sg = (g == 2) ? SCL2 : SCL1;
        const float* wr = w + tid * 125;
        float base = bi[tid] + bh[tid];
        float acc[8];
#pragma unroll
        for (int tt = 0; tt < 8; ++tt) acc[tt] = base;
        for (int k = 0; k < 125; ++k) {
            float wv = wr[k];
#pragma unroll
            for (int tt = 0; tt < 8; ++tt) acc[tt] += wv * xs[tt][k];
        }
#pragma unroll
        for (int tt = 0; tt < 8; ++tt) xg[(t0 + tt) * 512 + u * 4 + g] = acc[tt] * sg;
    } else {
        const int qq = tid - G4;
#pragma unroll
        for (int tt = 0; tt < 8; ++tt) xg[(t0 + tt) * 512 + G4 + qq] = 0.f;
    }
}

// ---------------------------------------------- layer-1 input GEMM (K=250)
__global__ __launch_bounds__(512) void ingemm4_k(
    const float* __restrict__ x,
    const float* __restrict__ wf, const float* __restrict__ bif, const float* __restrict__ bhf,
    const float* __restrict__ wb, const float* __restrict__ bib, const float* __restrict__ bhb,
    float* __restrict__ xg4f, float* __restrict__ xg4b)
{
    __shared__ float xs[8][250];
    const int dir = blockIdx.y;
    const float* __restrict__ w  = dir ? wb  : wf;
    const float* __restrict__ bi = dir ? bib : bif;
    const float* __restrict__ bh = dir ? bhb : bhf;
    float* __restrict__ xg       = dir ? xg4b : xg4f;

    const int t0  = blockIdx.x * 8;
    const int tid = threadIdx.x;
    for (int i = tid; i < 8 * 250; i += 512) {
        int r = i / 250;
        xs[r][i - r * 250] = x[t0 * 250 + i];
    }
    __syncthreads();

    if (tid < G4) {
        const int g = tid / 125;
        const int u = tid - g * 125;
        const float sg = (g == 2) ? SCL2 : SCL1;
        const float* wr = w + tid * 250;
        float base = bi[tid] + bh[tid];
        float acc[8];
#pragma unroll
        for (int tt = 0; tt < 8; ++tt) acc[tt] = base;
        for (int k = 0; k < 250; ++k) {
            float wv = wr[k];
#pragma unroll
            for (int tt = 0; tt < 8; ++tt) acc[tt] += wv * xs[tt][k];
        }
#pragma unroll
        for (int tt = 0; tt < 8; ++tt) xg[(t0 + tt) * 512 + u * 4 + g] = acc[tt] * sg;
    } else {
        const int qq = tid - G4;
#pragma unroll
        for (int tt = 0; tt < 8; ++tt) xg[(t0 + tt) * 512 + G4 + qq] = 0.f;
    }
}

// --------------------------------- Whh -> fp8(e4m3) MFMA A-fragment prep
// grid (32, 2 dirs, 2 layers) in one launch.
__global__ __launch_bounds__(64) void whhprep8_k(
    const float* __restrict__ w0f, const float* __restrict__ w0b,
    const float* __restrict__ w1f, const float* __restrict__ w1b,
    int* __restrict__ out0, int* __restrict__ out1)
{
    const int lay = blockIdx.z;
    const int dir = blockIdx.y;
    const float* __restrict__ whh = lay ? (dir ? w1b : w1f) : (dir ? w0b : w0f);
    int* __restrict__ out = lay ? out1 : out0;
    const int tg = blockIdx.x;        // 0..31
    const int l  = threadIdx.x;
    const int R  = tg * 16 + (l & 15);
    const int u  = R >> 2, g = R & 3;
    const float sg = (g == 2) ? SCL2 : SCL1;
    const int kb = (l >> 4) * 32;
    float f[32];
#pragma unroll
    for (int e = 0; e < 32; ++e) {
        const int k = kb + e;
        f[e] = (u < H && k < H) ? whh[(g * H + u) * H + k] * sg : 0.f;
    }
    int* dst = out + ((dir * 32 + tg) * 64 + l) * 8;
#pragma unroll
    for (int j = 0; j < 8; ++j) {
        int lo = __builtin_amdgcn_cvt_pk_fp8_f32(f[4 * j + 0], f[4 * j + 1], 0,  false);
        int wv = __builtin_amdgcn_cvt_pk_fp8_f32(f[4 * j + 2], f[4 * j + 3], lo, true);
        dst[j] = wv;
    }
}

// ------------------------------------------------------------ LSTM scan v10
// grid = 2 (dir), block = 512 (8 waves). Wave w: row-tiles 4w..4w+3
// (units 16w..16w+15), 4 MX MFMA/step (C = own-lane xg). Producer-consumer:
// seg1 all waves MFMA + writer lanes (c<4) publish gate f32x4 to gates[];
// seg2 waves 0-1 (setprio 1) activate one unit/lane, write fp8 h + hout.
__global__ __launch_bounds__(512, 1) void lstm_scan10_k(
    const float* __restrict__ xg_f, const float* __restrict__ xg_b,
    const int* __restrict__ whhA,
    float* __restrict__ hout)   // [NN][250]
{
    __shared__ __align__(16) unsigned char hb8[128];     // fp8 h
    __shared__ __align__(16) float gates[128 * 4];       // f32 gate vecs
    const int dir = blockIdx.x;
    const float* __restrict__ xg = dir ? xg_b : xg_f;
    const int col = dir ? H : 0;

    const int tid = threadIdx.x;
    const int w = tid >> 6;        // 0..7
    const int l = tid & 63;
    const int q = l >> 4;          // k-block / D-row group
    const int c = l & 15;          // replicated column

    const i32x8* Ab = (const i32x8*)whhA;
    i32x8 A0 = Ab[(dir * 32 + w * 4 + 0) * 64 + l];
    i32x8 A1 = Ab[(dir * 32 + w * 4 + 1) * 64 + l];
    i32x8 A2 = Ab[(dir * 32 + w * 4 + 2) * 64 + l];
    i32x8 A3 = Ab[(dir * 32 + w * 4 + 3) * 64 + l];

    if (tid < 128) hb8[tid] = 0;
    __syncthreads();
    if (tid < 128) __builtin_amdgcn_s_setprio(1);   // act waves favored

    const int usel = 16 * w + 4 * (c & 3) + q;   // unit of this lane's gv
    const bool writer = (c < 4);
    const int xoff = 4 * usel;

    float cst = 0.f;                 // live only in act lanes (tid<128)
    auto T = [&](int s) { return dir ? (NN - 1 - s) : s; };

    auto LOADX = [&](int s_) -> f32x4 {
        const int sc = (s_ < NN) ? s_ : NN - 1;
        return *(const f32x4*)(xg + T(sc) * 512 + xoff);
    };

    auto STEP = [&](int t, f32x4 x) {
        // ---- seg1: MFMA + gate publish (all waves)
        i32x8 B = *(const i32x8*)(hb8 + 32 * q);
        f32x4 a0 = __builtin_amdgcn_mfma_scale_f32_16x16x128_f8f6f4(
            A0, B, x, 0, 0, 0, 0x7F7F7F7F, 0, 0x7F7F7F7F);
        f32x4 a1 = __builtin_amdgcn_mfma_scale_f32_16x16x128_f8f6f4(
            A1, B, x, 0, 0, 0, 0x7F7F7F7F, 0, 0x7F7F7F7F);
        f32x4 a2 = __builtin_amdgcn_mfma_scale_f32_16x16x128_f8f6f4(
            A2, B, x, 0, 0, 0, 0x7F7F7F7F, 0, 0x7F7F7F7F);
        f32x4 a3 = __builtin_amdgcn_mfma_scale_f32_16x16x128_f8f6f4(
            A3, B, x, 0, 0, 0, 0x7F7F7F7F, 0, 0x7F7F7F7F);
        if (writer) {
            f32x4 s0 = (c & 1) ? a1 : a0;
            f32x4 s1 = (c & 1) ? a3 : a2;
            f32x4 gv = (c & 2) ? s1 : s0;
            *(f32x4*)(gates + 4 * usel) = gv;
        }
        asm volatile("s_waitcnt lgkmcnt(0)" ::: "memory");
        __builtin_amdgcn_s_barrier();
        __builtin_amdgcn_sched_barrier(0);
        // ---- seg2: activation (waves 0-1 only; one lane per unit)
        if (tid < 128) {
            f32x4 g = *(const f32x4*)(gates + 4 * tid);
            const float ai = frcp(1.f + fexp2(g.x));
            const float af = frcp(1.f + fexp2(g.y));
            const float sgm = frcp(1.f + fexp2(g.z));
            const float ao = frcp(1.f + fexp2(g.w));
            const float ag = __builtin_fmaf(2.f, sgm, -1.f);
            cst = __builtin_fmaf(af, cst, ai * ag);
            const float r = frcp(1.f + fexp2(cst * SCL2));
            const float hv = __builtin_fmaf(2.f * ao, r, -ao);   // ao*(2r-1)
            int pk = __builtin_amdgcn_cvt_pk_fp8_f32(hv, 0.f, 0, false);
            hb8[tid] = (unsigned char)(pk & 0xFF);
            if (tid < H) hout[t * 250 + col + tid] = hv;
        }
        asm volatile("s_waitcnt lgkmcnt(0)" ::: "memory");
        __builtin_amdgcn_s_barrier();
        __builtin_amdgcn_sched_barrier(0);
    };

    f32x4 p0 = LOADX(0), p1 = LOADX(1);
#pragma unroll 1
    for (int s = 0; s < NN; s += 4) {
        f32x4 n0 = LOADX(s + 2), n1 = LOADX(s + 3);
        STEP(T(s),     p0);
        STEP(T(s + 1), p1);
        p0 = LOADX(s + 4); p1 = LOADX(s + 5);
        STEP(T(s + 2), n0);
        STEP(T(s + 3), n1);
    }
}

// --------------------------------------------- heads/mods: h1@w.T + b
__global__ __launch_bounds__(256) void headmod_k(
    const float* __restrict__ h1,
    const float* __restrict__ w1, const float* __restrict__ b1,
    const float* __restrict__ w2, const float* __restrict__ b2,
    float* __restrict__ heads, float* __restrict__ mods)
{
    __shared__ float xs[8][250];
    const int t0  = blockIdx.x * 8;
    const int tid = threadIdx.x;
    for (int i = tid; i < 8 * 250; i += 256) {
        int r = i / 250;
        xs[r][i - r * 250] = h1[t0 * 250 + i];
    }
    __syncthreads();

    int d; const float* w; float bb; float* o;
    if (tid < DMLP)                          { d = tid;       w = w1 + d * 250; bb = b1[d]; o = heads; }
    else if (tid >= 128 && tid < 128 + DMLP) { d = tid - 128; w = w2 + d * 250; bb = b2[d]; o = mods;  }
    else return;

    float acc[8];
#pragma unroll
    for (int tt = 0; tt < 8; ++tt) acc[tt] = bb;
    for (int k = 0; k < 250; ++k) {
        float wv = w[k];
#pragma unroll
        for (int tt = 0; tt < 8; ++tt) acc[tt] += wv * xs[tt][k];
    }
#pragma unroll
    for (int tt = 0; tt < 8; ++tt) o[(t0 + tt) * DMLP + d] = acc[tt];
}

// ----------------------------------------------------------------- scores
__global__ __launch_bounds__(256) void scores_k(
    const float* __restrict__ heads, const float* __restrict__ mods,
    const float* __restrict__ w3, const float* __restrict__ b3,
    float* __restrict__ out)
{
    __shared__ __align__(16) float hh[16][DMLP];
    __shared__ __align__(16) float mm[16][DMLP];
    __shared__ __align__(16) float ws3[DMLP];
    const int bh = blockIdx.y * 16, bm = blockIdx.x * 16;
    const int tid = threadIdx.x;
    for (int i = tid; i < 16 * DMLP; i += 256) {
        int r = i / DMLP, d = i - r * DMLP;
        hh[r][d] = heads[(bh + r) * DMLP + d];
        mm[r][d] = mods[(bm + r) * DMLP + d];
    }
    if (tid < DMLP) ws3[tid] = w3[tid];
    __syncthreads();

    const int tx = tid & 15, ty = tid >> 4;
    const f32x4* h4 = (const f32x4*)hh[ty];
    const f32x4* m4 = (const f32x4*)mm[tx];
    const f32x4* w4 = (const f32x4*)ws3;
    float acc = 0.f;
#pragma unroll
    for (int qq = 0; qq < DMLP / 4; ++qq) {
        f32x4 v  = h4[qq] + m4[qq];
        f32x4 wv = w4[qq];
#pragma unroll
        for (int e = 0; e < 4; ++e) {
            float th = 2.f * frcp(1.f + fexp2(v[e] * SCL2)) - 1.f;
            acc += wv[e] * th;
        }
    }
    acc += b3[0];
    const int hrow = bh + ty, mcol = bm + tx;
    float v = (hrow == mcol) ? -3.3895313892515355e38f : bf16_quant(acc);
    out[hrow * NN + mcol] = v;
}

// ----------------------------------------------------------------- launch
extern "C" void kernel_launch(void* const* d_in, const int* in_sizes, int n_in,
                              void* d_out, int out_size, void* d_ws, size_t ws_size,
                              hipStream_t stream)
{
    const int*   wid   = (const int*)d_in[0];
    const int*   pid   = (const int*)d_in[1];
    const float* wemb  = (const float*)d_in[3];
    const float* pemb  = (const float*)d_in[4];
    const float* wih0f = (const float*)d_in[5];
    const float* whh0f = (const float*)d_in[6];
    const float* bih0f = (const float*)d_in[7];
    const float* bhh0f = (const float*)d_in[8];
    const float* wih0b = (const float*)d_in[9];
    const float* whh0b = (const float*)d_in[10];
    const float* bih0b = (const float*)d_in[11];
    const float* bhh0b = (const float*)d_in[12];
    const float* wih1f = (const float*)d_in[13];
    const float* whh1f = (const float*)d_in[14];
    const float* bih1f = (const float*)d_in[15];
    const float* bhh1f = (const float*)d_in[16];
    const float* wih1b = (const float*)d_in[17];
    const float* whh1b = (const float*)d_in[18];
    const float* bih1b = (const float*)d_in[19];
    const float* bhh1b = (const float*)d_in[20];
    const float* w1    = (const float*)d_in[21];
    const float* b1    = (const float*)d_in[22];
    const float* w2    = (const float*)d_in[23];
    const float* b2    = (const float*)d_in[24];
    const float* w3    = (const float*)d_in[25];
    const float* b3    = (const float*)d_in[26];

    float* ws    = (float*)d_ws;
    float* xgf   = ws;                  // 524288
    float* xgb   = ws + 524288;         // 524288
    float* h0    = ws + 1048576;        // 256000
    float* h1    = ws + 1304576;        // 256000
    float* hd    = ws + 1560576;        // 102400
    float* md    = ws + 1662976;        // 102400
    int*   whhA0 = (int*)(ws + 1765376);  // 32768 i32
    int*   whhA1 = (int*)(ws + 1798144);  // 32768 i32

    whhprep8_k<<<dim3(32, 2, 2), 64, 0, stream>>>(
        whh0f, whh0b, whh1f, whh1b, whhA0, whhA1);

    ingemm4a_k<<<dim3(NN / 8, 2), 512, 0, stream>>>(
        wid, pid, wemb, pemb,
        wih0f, bih0f, bhh0f, wih0b, bih0b, bhh0b, xgf, xgb);

    lstm_scan10_k<<<2, 512, 0, stream>>>(xgf, xgb, whhA0, h0);

    ingemm4_k<<<dim3(NN / 8, 2), 512, 0, stream>>>(
        h0, wih1f, bih1f, bhh1f, wih1b, bih1b, bhh1b, xgf, xgb);

    lstm_scan10_k<<<2, 512, 0, stream>>>(xgf, xgb, whhA1, h1);

    headmod_k<<<NN / 8, 256, 0, stream>>>(h1, w1, b1, w2, b2, hd, md);

    scores_k<<<dim3(NN / 16, NN / 16), 256, 0, stream>>>(hd, md, w3, b3, (float*)d_out);
}

// Round 14
// 866.399 us; speedup vs baseline: 1.4153x; 1.1588x over previous
//
#include <hip/hip_runtime.h>
#include <hip/hip_bf16.h>

#define H 125
#define G4 500      // 4*H
#define NN 1024
#define DMLP 100

// exp-argument scales folded into weights/xg: sigmoid(x) = rcp(1 + 2^(-x*log2e))
#define SCL1 (-1.4426950408889634f)   // i, f, o rows
#define SCL2 (-2.8853900817779268f)   // g rows (tanh = 2*sigmoid(2x)-1)

typedef __attribute__((ext_vector_type(4))) float f32x4;
typedef __attribute__((ext_vector_type(4))) int   i32x4;
typedef __attribute__((ext_vector_type(8))) int   i32x8;

__device__ __forceinline__ float frcp(float x) { return __builtin_amdgcn_rcpf(x); }
__device__ __forceinline__ float fexp2(float x) {
    float r;
    asm("v_exp_f32 %0, %1" : "=v"(r) : "v"(x));
    return r;
}

// f32 -> f32 rounded to bf16 precision (low 16 mantissa bits zero).
__device__ __forceinline__ float bf16_quant(float v) {
    return __bfloat162float(__float2bfloat16(v));
}

// ----------------- layer-0 input GEMM with fused embedding gather
__global__ __launch_bounds__(512) void ingemm4a_k(
    const int* __restrict__ wid, const int* __restrict__ pid,
    const float* __restrict__ wemb, const float* __restrict__ pemb,
    const float* __restrict__ wf, const float* __restrict__ bif, const float* __restrict__ bhf,
    const float* __restrict__ wb, const float* __restrict__ bib, const float* __restrict__ bhb,
    float* __restrict__ xg4f, float* __restrict__ xg4b)
{
    __shared__ float xs[8][125];
    const int dir = blockIdx.y;
    const float* __restrict__ w  = dir ? wb  : wf;
    const float* __restrict__ bi = dir ? bib : bif;
    const float* __restrict__ bh = dir ? bhb : bhf;
    float* __restrict__ xg       = dir ? xg4b : xg4f;

    const int t0  = blockIdx.x * 8;
    const int tid = threadIdx.x;
    for (int i = tid; i < 8 * 125; i += 512) {
        int r = i / 125, k = i - r * 125;
        int t = t0 + r;
        xs[r][k] = (k < 100) ? wemb[wid[t] * 100 + k] : pemb[pid[t] * 25 + (k - 100)];
    }
    __syncthreads();

    if (tid < G4) {
        const int g = tid / 125;
        const int u = tid - g * 125;
        const float sg = (g == 2) ? SCL2 : SCL1;
        const float* wr = w + tid * 125;
        float base = bi[tid] + bh[tid];
        float acc[8];
#pragma unroll
        for (int tt = 0; tt < 8; ++tt) acc[tt] = base;
        for (int k = 0; k < 125; ++k) {
            float wv = wr[k];
#pragma unroll
            for (int tt = 0; tt < 8; ++tt) acc[tt] += wv * xs[tt][k];
        }
#pragma unroll
        for (int tt = 0; tt < 8; ++tt) xg[(t0 + tt) * 512 + u * 4 + g] = acc[tt] * sg;
    } else {
        const int qq = tid - G4;
#pragma unroll
        for (int tt = 0; tt < 8; ++tt) xg[(t0 + tt) * 512 + G4 + qq] = 0.f;
    }
}

// ---------------------------------------------- layer-1 input GEMM (K=250)
__global__ __launch_bounds__(512) void ingemm4_k(
    const float* __restrict__ x,
    const float* __restrict__ wf, const float* __restrict__ bif, const float* __restrict__ bhf,
    const float* __restrict__ wb, const float* __restrict__ bib, const float* __restrict__ bhb,
    float* __restrict__ xg4f, float* __restrict__ xg4b)
{
    __shared__ float xs[8][250];
    const int dir = blockIdx.y;
    const float* __restrict__ w  = dir ? wb  : wf;
    const float* __restrict__ bi = dir ? bib : bif;
    const float* __restrict__ bh = dir ? bhb : bhf;
    float* __restrict__ xg       = dir ? xg4b : xg4f;

    const int t0  = blockIdx.x * 8;
    const int tid = threadIdx.x;
    for (int i = tid; i < 8 * 250; i += 512) {
        int r = i / 250;
        xs[r][i - r * 250] = x[t0 * 250 + i];
    }
    __syncthreads();

    if (tid < G4) {
        const int g = tid / 125;
        const int u = tid - g * 125;
        const float sg = (g == 2) ? SCL2 : SCL1;
        const float* wr = w + tid * 250;
        float base = bi[tid] + bh[tid];
        float acc[8];
#pragma unroll
        for (int tt = 0; tt < 8; ++tt) acc[tt] = base;
        for (int k = 0; k < 250; ++k) {
            float wv = wr[k];
#pragma unroll
            for (int tt = 0; tt < 8; ++tt) acc[tt] += wv * xs[tt][k];
        }
#pragma unroll
        for (int tt = 0; tt < 8; ++tt) xg[(t0 + tt) * 512 + u * 4 + g] = acc[tt] * sg;
    } else {
        const int qq = tid - G4;
#pragma unroll
        for (int tt = 0; tt < 8; ++tt) xg[(t0 + tt) * 512 + G4 + qq] = 0.f;
    }
}

// --------------------------------- Whh -> fp8(e4m3) MFMA A-fragment prep
// grid (32, 2 dirs, 2 layers) in one launch.
__global__ __launch_bounds__(64) void whhprep8_k(
    const float* __restrict__ w0f, const float* __restrict__ w0b,
    const float* __restrict__ w1f, const float* __restrict__ w1b,
    int* __restrict__ out0, int* __restrict__ out1)
{
    const int lay = blockIdx.z;
    const int dir = blockIdx.y;
    const float* __restrict__ whh = lay ? (dir ? w1b : w1f) : (dir ? w0b : w0f);
    int* __restrict__ out = lay ? out1 : out0;
    const int tg = blockIdx.x;        // 0..31
    const int l  = threadIdx.x;
    const int R  = tg * 16 + (l & 15);
    const int u  = R >> 2, g = R & 3;
    const float sg = (g == 2) ? SCL2 : SCL1;
    const int kb = (l >> 4) * 32;
    float f[32];
#pragma unroll
    for (int e = 0; e < 32; ++e) {
        const int k = kb + e;
        f[e] = (u < H && k < H) ? whh[(g * H + u) * H + k] * sg : 0.f;
    }
    int* dst = out + ((dir * 32 + tg) * 64 + l) * 8;
#pragma unroll
    for (int j = 0; j < 8; ++j) {
        int lo = __builtin_amdgcn_cvt_pk_fp8_f32(f[4 * j + 0], f[4 * j + 1], 0,  false);
        int wv = __builtin_amdgcn_cvt_pk_fp8_f32(f[4 * j + 2], f[4 * j + 3], lo, true);
        dst[j] = wv;
    }
}

// ------------------------------------------------------------ LSTM scan v11
// grid = 2 (dir), block = 512 (8 waves). Wave w: row-tiles 4w..4w+3
// (units 16w..16w+15), 4 MX MFMA/step (C = own-lane xg). SINGLE barrier/step:
// activation runs in the OWNING wave's writer lanes (c<4) right after its own
// MFMA - no gates round-trip. h double-buffered (read pp, write pp^1).
__global__ __launch_bounds__(512, 1) void lstm_scan11_k(
    const float* __restrict__ xg_f, const float* __restrict__ xg_b,
    const int* __restrict__ whhA,
    float* __restrict__ hout)   // [NN][250]
{
    __shared__ __align__(16) unsigned char hb8[2][128];   // fp8 h, double buf
    const int dir = blockIdx.x;
    const float* __restrict__ xg = dir ? xg_b : xg_f;
    const int col = dir ? H : 0;

    const int tid = threadIdx.x;
    const int w = tid >> 6;        // 0..7
    const int l = tid & 63;
    const int q = l >> 4;          // k-block / D-row group
    const int c = l & 15;          // replicated column

    const i32x8* Ab = (const i32x8*)whhA;
    i32x8 A0 = Ab[(dir * 32 + w * 4 + 0) * 64 + l];
    i32x8 A1 = Ab[(dir * 32 + w * 4 + 1) * 64 + l];
    i32x8 A2 = Ab[(dir * 32 + w * 4 + 2) * 64 + l];
    i32x8 A3 = Ab[(dir * 32 + w * 4 + 3) * 64 + l];

    if (tid < 256) ((unsigned char*)hb8)[tid] = 0;
    __syncthreads();

    const int usel = 16 * w + 4 * (c & 3) + q;   // unit of this lane's gv
    const bool writer = (c < 4);
    const int xoff = 4 * usel;

    float cst = 0.f;               // meaningful only on writer lanes
    int pp = 0;
    auto T = [&](int s) { return dir ? (NN - 1 - s) : s; };

    auto LOADX = [&](int s_) -> f32x4 {
        const int sc = (s_ < NN) ? s_ : NN - 1;
        return *(const f32x4*)(xg + T(sc) * 512 + xoff);
    };

    auto STEP = [&](int t, f32x4 x) {
        i32x8 B = *(const i32x8*)(hb8[pp] + 32 * q);
        f32x4 a0 = __builtin_amdgcn_mfma_scale_f32_16x16x128_f8f6f4(
            A0, B, x, 0, 0, 0, 0x7F7F7F7F, 0, 0x7F7F7F7F);
        f32x4 a1 = __builtin_amdgcn_mfma_scale_f32_16x16x128_f8f6f4(
            A1, B, x, 0, 0, 0, 0x7F7F7F7F, 0, 0x7F7F7F7F);
        f32x4 a2 = __builtin_amdgcn_mfma_scale_f32_16x16x128_f8f6f4(
            A2, B, x, 0, 0, 0, 0x7F7F7F7F, 0, 0x7F7F7F7F);
        f32x4 a3 = __builtin_amdgcn_mfma_scale_f32_16x16x128_f8f6f4(
            A3, B, x, 0, 0, 0, 0x7F7F7F7F, 0, 0x7F7F7F7F);

        float hv = 0.f;
        if (writer) {
            f32x4 s0 = (c & 1) ? a1 : a0;
            f32x4 s1 = (c & 1) ? a3 : a2;
            f32x4 gv = (c & 2) ? s1 : s0;
            const float ai  = frcp(1.f + fexp2(gv.x));
            const float af  = frcp(1.f + fexp2(gv.y));
            const float sgm = frcp(1.f + fexp2(gv.z));
            const float ao  = frcp(1.f + fexp2(gv.w));
            const float ag  = __builtin_fmaf(2.f, sgm, -1.f);
            cst = __builtin_fmaf(af, cst, ai * ag);
            const float r = frcp(1.f + fexp2(cst * SCL2));
            hv = __builtin_fmaf(2.f * ao, r, -ao);   // ao*(2r-1)
            int pk = __builtin_amdgcn_cvt_pk_fp8_f32(hv, 0.f, 0, false);
            hb8[pp ^ 1][usel] = (unsigned char)(pk & 0xFF);
        }
        asm volatile("s_waitcnt lgkmcnt(0)" ::: "memory");
        __builtin_amdgcn_s_barrier();
        __builtin_amdgcn_sched_barrier(0);
        if (writer && usel < H) hout[t * 250 + col + usel] = hv;
        pp ^= 1;
    };

    f32x4 p0 = LOADX(0), p1 = LOADX(1);
#pragma unroll 1
    for (int s = 0; s < NN; s += 4) {
        f32x4 n0 = LOADX(s + 2), n1 = LOADX(s + 3);
        STEP(T(s),     p0);
        STEP(T(s + 1), p1);
        p0 = LOADX(s + 4); p1 = LOADX(s + 5);
        STEP(T(s + 2), n0);
        STEP(T(s + 3), n1);
    }
}

// --------------------------------------------- heads/mods: h1@w.T + b
__global__ __launch_bounds__(256) void headmod_k(
    const float* __restrict__ h1,
    const float* __restrict__ w1, const float* __restrict__ b1,
    const float* __restrict__ w2, const float* __restrict__ b2,
    float* __restrict__ heads, float* __restrict__ mods)
{
    __shared__ float xs[8][250];
    const int t0  = blockIdx.x * 8;
    const int tid = threadIdx.x;
    for (int i = tid; i < 8 * 250; i += 256) {
        int r = i / 250;
        xs[r][i - r * 250] = h1[t0 * 250 + i];
    }
    __syncthreads();

    int d; const float* w; float bb; float* o;
    if (tid < DMLP)                          { d = tid;       w = w1 + d * 250; bb = b1[d]; o = heads; }
    else if (tid >= 128 && tid < 128 + DMLP) { d = tid - 128; w = w2 + d * 250; bb = b2[d]; o = mods;  }
    else return;

    float acc[8];
#pragma unroll
    for (int tt = 0; tt < 8; ++tt) acc[tt] = bb;
    for (int k = 0; k < 250; ++k) {
        float wv = w[k];
#pragma unroll
        for (int tt = 0; tt < 8; ++tt) acc[tt] += wv * xs[tt][k];
    }
#pragma unroll
    for (int tt = 0; tt < 8; ++tt) o[(t0 + tt) * DMLP + d] = acc[tt];
}

// ----------------------------------------------------------------- scores
__global__ __launch_bounds__(256) void scores_k(
    const float* __restrict__ heads, const float* __restrict__ mods,
    const float* __restrict__ w3, const float* __restrict__ b3,
    float* __restrict__ out)
{
    __shared__ __align__(16) float hh[16][DMLP];
    __shared__ __align__(16) float mm[16][DMLP];
    __shared__ __align__(16) float ws3[DMLP];
    const int bh = blockIdx.y * 16, bm = blockIdx.x * 16;
    const int tid = threadIdx.x;
    for (int i = tid; i < 16 * DMLP; i += 256) {
        int r = i / DMLP, d = i - r * DMLP;
        hh[r][d] = heads[(bh + r) * DMLP + d];
        mm[r][d] = mods[(bm + r) * DMLP + d];
    }
    if (tid < DMLP) ws3[tid] = w3[tid];
    __syncthreads();

    const int tx = tid & 15, ty = tid >> 4;
    const f32x4* h4 = (const f32x4*)hh[ty];
    const f32x4* m4 = (const f32x4*)mm[tx];
    const f32x4* w4 = (const f32x4*)ws3;
    float acc = 0.f;
#pragma unroll
    for (int qq = 0; qq < DMLP / 4; ++qq) {
        f32x4 v  = h4[qq] + m4[qq];
        f32x4 wv = w4[qq];
#pragma unroll
        for (int e = 0; e < 4; ++e) {
            float th = 2.f * frcp(1.f + fexp2(v[e] * SCL2)) - 1.f;
            acc += wv[e] * th;
        }
    }
    acc += b3[0];
    const int hrow = bh + ty, mcol = bm + tx;
    float v = (hrow == mcol) ? -3.3895313892515355e38f : bf16_quant(acc);
    out[hrow * NN + mcol] = v;
}

// ----------------------------------------------------------------- launch
extern "C" void kernel_launch(void* const* d_in, const int* in_sizes, int n_in,
                              void* d_out, int out_size, void* d_ws, size_t ws_size,
                              hipStream_t stream)
{
    const int*   wid   = (const int*)d_in[0];
    const int*   pid   = (const int*)d_in[1];
    const float* wemb  = (const float*)d_in[3];
    const float* pemb  = (const float*)d_in[4];
    const float* wih0f = (const float*)d_in[5];
    const float* whh0f = (const float*)d_in[6];
    const float* bih0f = (const float*)d_in[7];
    const float* bhh0f = (const float*)d_in[8];
    const float* wih0b = (const float*)d_in[9];
    const float* whh0b = (const float*)d_in[10];
    const float* bih0b = (const float*)d_in[11];
    const float* bhh0b = (const float*)d_in[12];
    const float* wih1f = (const float*)d_in[13];
    const float* whh1f = (const float*)d_in[14];
    const float* bih1f = (const float*)d_in[15];
    const float* bhh1f = (const float*)d_in[16];
    const float* wih1b = (const float*)d_in[17];
    const float* whh1b = (const float*)d_in[18];
    const float* bih1b = (const float*)d_in[19];
    const float* bhh1b = (const float*)d_in[20];
    const float* w1    = (const float*)d_in[21];
    const float* b1    = (const float*)d_in[22];
    const float* w2    = (const float*)d_in[23];
    const float* b2    = (const float*)d_in[24];
    const float* w3    = (const float*)d_in[25];
    const float* b3    = (const float*)d_in[26];

    float* ws    = (float*)d_ws;
    float* xgf   = ws;                  // 524288
    float* xgb   = ws + 524288;         // 524288
    float* h0    = ws + 1048576;        // 256000
    float* h1    = ws + 1304576;        // 256000
    float* hd    = ws + 1560576;        // 102400
    float* md    = ws + 1662976;        // 102400
    int*   whhA0 = (int*)(ws + 1765376);  // 32768 i32
    int*   whhA1 = (int*)(ws + 1798144);  // 32768 i32

    whhprep8_k<<<dim3(32, 2, 2), 64, 0, stream>>>(
        whh0f, whh0b, whh1f, whh1b, whhA0, whhA1);

    ingemm4a_k<<<dim3(NN / 8, 2), 512, 0, stream>>>(
        wid, pid, wemb, pemb,
        wih0f, bih0f, bhh0f, wih0b, bih0b, bhh0b, xgf, xgb);

    lstm_scan11_k<<<2, 512, 0, stream>>>(xgf, xgb, whhA0, h0);

    ingemm4_k<<<dim3(NN / 8, 2), 512, 0, stream>>>(
        h0, wih1f, bih1f, bhh1f, wih1b, bih1b, bhh1b, xgf, xgb);

    lstm_scan11_k<<<2, 512, 0, stream>>>(xgf, xgb, whhA1, h1);

    headmod_k<<<NN / 8, 256, 0, stream>>>(h1, w1, b1, w2, b2, hd, md);

    scores_k<<<dim3(NN / 16, NN / 16), 256, 0, stream>>>(hd, md, w3, b3, (float*)d_out);
}